// Round 8
// baseline (182.880 us; speedup 1.0000x reference)
//
#include <hip/hip_runtime.h>
#include <hip/hip_cooperative_groups.h>

namespace cg = cooperative_groups;

typedef __bf16 bf16x8 __attribute__((ext_vector_type(8)));
typedef float f32x4 __attribute__((ext_vector_type(4)));

#define TWO_LOG2E 2.88539008177792681f   // 2*log2(e): exp(2x) = exp2(x*TWO_LOG2E)

#define GLOADLDS16(g, l) __builtin_amdgcn_global_load_lds(                     \
    (const __attribute__((address_space(1))) void*)(g),                        \
    (__attribute__((address_space(3))) void*)(l), 16, 0, 0)

__device__ __forceinline__ unsigned f2bf(float f) {
    unsigned u = __float_as_uint(f);
    return (u + 0x7FFFu + ((u >> 16) & 1u)) >> 16;   // RNE
}

// ================= phase 1: normalize z=[z1;z2] -> bf16 zn; zero S/out =================
__device__ __forceinline__ void phase1(const float* __restrict__ z1,
                                       const float* __restrict__ z2,
                                       unsigned short* __restrict__ zn,
                                       float* __restrict__ S,
                                       float* __restrict__ out) {
    const int tid = threadIdx.x, lane = tid & 63, wave = tid >> 6;
    for (int grp = blockIdx.x; grp < 512; grp += gridDim.x) {   // 16-row groups
        if (tid < 16) S[(grp << 4) + tid] = 0.f;
        if (grp == 0 && tid == 0) out[0] = 0.f;
#pragma unroll
        for (int r = 0; r < 4; ++r) {
            int row = (grp << 4) + (wave << 2) + r;
            const float* src = (row < 4096) ? (z1 + row * 256) : (z2 + (row - 4096) * 256);
            float4 v = ((const float4*)src)[lane];
            float ss = v.x * v.x + v.y * v.y + v.z * v.z + v.w * v.w;
#pragma unroll
            for (int m = 32; m > 0; m >>= 1) ss += __shfl_xor(ss, m, 64);
            float sc = 1.0f / fmaxf(sqrtf(ss), 1e-8f);
            uint2 w;
            w.x = f2bf(v.x * sc) | (f2bf(v.y * sc) << 16);
            w.y = f2bf(v.z * sc) | (f2bf(v.w * sc) << 16);
            *(uint2*)(zn + row * 256 + (lane << 2)) = w;
        }
    }
}

// ================= phase 2: FULL-SQUARE sim-exp, uniform streaming pipeline =============
// 512 jobs: job = strip(64) x colRun(8) = 128 rows x 1024 cols = 16 tiles of 64 cols
// = 32 K-halves, one steady double-buffered pipeline. Each of the 4 waves owns 32 rows
// x all 64 cols: A = a[2][8] = 64 VGPRs (R7's a[4][8]=128 pushed the unified VGPR+AGPR
// total past 256 -> 1 block/CU, occupancy 11%, everything latency-exposed). Total regs
// ~170 -> (256,2) fits without spill -> 2 blocks/CU, barrier drains overlap across waves.
// Row sums in registers; ONE atomic flush per job. Diagonal handled in phase 3.
__device__ __forceinline__ void phase2(const unsigned short* __restrict__ zn,
                                       float* __restrict__ S,
                                       unsigned short* __restrict__ Bs) {
    const int tid = threadIdx.x, lane = tid & 63, wave = tid >> 6;
    const int q = lane >> 4, n16 = lane & 15;
    const int G = gridDim.x;

    // stage one 16KB half: 64 cols x 128 k-elems, chunk-swizzled (slot = src ^ (c&15))
    auto stage = [&](int colBase, int h, int buf) {
        unsigned short* base = Bs + (buf << 13);
#pragma unroll
        for (int p = 0; p < 4; ++p) {
            int s16 = (p << 8) + tid;               // dest 16B slot 0..1023
            int c   = s16 >> 4;                     // col 0..63
            int k8  = (s16 & 15) ^ (c & 15);        // source chunk within half
            GLOADLDS16(zn + ((colBase + c) << 8) + (h << 7) + (k8 << 3),
                       base + (s16 << 3));
        }
    };

    for (int job = blockIdx.x; job < 512; job += G) {
        const int rowBase = (job >> 3) << 7;        // strip * 128
        const int colRun  = (job & 7) << 10;        // run * 1024

        // A: wave's 32 rows x K=256 in registers (64 VGPRs)
        bf16x8 a[2][8];
#pragma unroll
        for (int rt = 0; rt < 2; ++rt)
#pragma unroll
            for (int ks = 0; ks < 8; ++ks)
                a[rt][ks] = *(const bf16x8*)(zn
                    + ((rowBase + (wave << 5) + (rt << 4) + n16) << 8)
                    + (ks << 5) + (q << 3));

        float rs[2][4];
#pragma unroll
        for (int i = 0; i < 2; ++i)
#pragma unroll
            for (int j = 0; j < 4; ++j) rs[i][j] = 0.f;

        stage(colRun, 0, 0);
        int buf = 0;

        for (int tile = 0; tile < 16; ++tile) {
            f32x4 acc[2][4];
#pragma unroll
            for (int rt = 0; rt < 2; ++rt)
#pragma unroll
                for (int ct = 0; ct < 4; ++ct) acc[rt][ct] = (f32x4){0.f, 0.f, 0.f, 0.f};

#pragma unroll
            for (int h = 0; h < 2; ++h) {
                __syncthreads();                    // current buf staged (loads are old)
                int m = (tile << 1) + h + 1;        // next half index
                if (m < 32) stage(colRun + ((m >> 1) << 6), m & 1, buf ^ 1);

                const unsigned short* bb = Bs + (buf << 13);
#pragma unroll
                for (int ksl = 0; ksl < 4; ++ksl) {
                    int k8 = ((ksl << 2) | q) ^ n16;
                    bf16x8 bf[4];
#pragma unroll
                    for (int ct = 0; ct < 4; ++ct) {
                        int c = (ct << 4) + n16;
                        bf[ct] = *(const bf16x8*)(bb + (((c << 4) | k8) << 3));
                    }
#pragma unroll
                    for (int rt = 0; rt < 2; ++rt)
#pragma unroll
                        for (int ct = 0; ct < 4; ++ct)
                            acc[rt][ct] = __builtin_amdgcn_mfma_f32_16x16x32_bf16(
                                a[rt][(h << 2) + ksl], bf[ct], acc[rt][ct], 0, 0, 0);
                }
                buf ^= 1;
            }

            // epilogue: rowsum += exp(2*dot) — registers only, no branches
#pragma unroll
            for (int rt = 0; rt < 2; ++rt)
#pragma unroll
                for (int ct = 0; ct < 4; ++ct)
#pragma unroll
                    for (int r = 0; r < 4; ++r)
                        rs[rt][r] += __builtin_amdgcn_exp2f(acc[rt][ct][r] * TWO_LOG2E);
        }

        // flush row sums once per job (C/D layout: col=n16, row=q*4+r)
        const int base = rowBase + (wave << 5) + (q << 2);
#pragma unroll
        for (int rt = 0; rt < 2; ++rt)
#pragma unroll
            for (int r = 0; r < 4; ++r) {
                float s = rs[rt][r];
                s += __shfl_xor(s, 1, 64);
                s += __shfl_xor(s, 2, 64);
                s += __shfl_xor(s, 4, 64);
                s += __shfl_xor(s, 8, 64);
                if (n16 == 0) atomicAdd(&S[base + (rt << 4) + r], s);
            }
    }
}

// ================= phase 3: loss = mean( log(S_i - e^{sim_ii}) - sim_{i,tar} ) ==========
__device__ __forceinline__ void phase3(const unsigned short* __restrict__ zn,
                                       const float* __restrict__ S,
                                       float* __restrict__ out,
                                       float* __restrict__ vals) {
    const int tid = threadIdx.x, lane = tid & 63, wave = tid >> 6;
    const int q = lane >> 4, n16 = lane & 15;
    const int rib = (wave << 2) + q;                // 0..15 rows per group
    for (int grp = blockIdx.x; grp < 512; grp += gridDim.x) {
        int row = (grp << 4) + rib;
        int tar = (row + 4096) & 8191;
        float drr = 0.f, drt = 0.f;
#pragma unroll
        for (int i = 0; i < 4; ++i) {
            int k = (i << 6) + (n16 << 2);
            uint2 ur = *(const uint2*)(zn + (row << 8) + k);
            uint2 ut = *(const uint2*)(zn + (tar << 8) + k);
            float a0 = __uint_as_float(ur.x << 16),  a1 = __uint_as_float(ur.x & 0xFFFF0000u);
            float a2 = __uint_as_float(ur.y << 16),  a3 = __uint_as_float(ur.y & 0xFFFF0000u);
            float b0 = __uint_as_float(ut.x << 16),  b1 = __uint_as_float(ut.x & 0xFFFF0000u);
            float b2 = __uint_as_float(ut.y << 16),  b3 = __uint_as_float(ut.y & 0xFFFF0000u);
            drr += a0 * a0 + a1 * a1 + a2 * a2 + a3 * a3;
            drt += a0 * b0 + a1 * b1 + a2 * b2 + a3 * b3;
        }
#pragma unroll
        for (int m = 1; m <= 8; m <<= 1) {
            drr += __shfl_xor(drr, m, 64);
            drt += __shfl_xor(drt, m, 64);
        }
        __syncthreads();
        if (n16 == 0) {
            float Sv = S[row] - __builtin_amdgcn_exp2f(drr * TWO_LOG2E);  // drop diagonal
            vals[rib] = 0.693147180559945f * __builtin_amdgcn_logf(Sv) - 2.0f * drt;
        }
        __syncthreads();
        if (tid == 0) {
            float s = 0.f;
#pragma unroll
            for (int i = 0; i < 16; ++i) s += vals[i];
            atomicAdd(out, s * (1.0f / 8192.0f));
        }
    }
}

// ================= kernels ==============================================================
// (256,2): 256-reg/wave cap. a[2][8]=64 + acc 32 + misc ~ 170 total -> fits, 2 blocks/CU.
__global__ void __launch_bounds__(256, 2) ntxent_fused(
    const float* __restrict__ z1, const float* __restrict__ z2,
    unsigned short* __restrict__ zn, float* __restrict__ S, float* __restrict__ out)
{
    __shared__ __align__(16) unsigned short Bs[2][8192];   // 2 x 16 KB
    phase1(z1, z2, zn, S, out);
    cg::this_grid().sync();
    phase2(zn, S, &Bs[0][0]);
    cg::this_grid().sync();
    phase3(zn, S, out, (float*)&Bs[0][0]);
}

__global__ void __launch_bounds__(256, 2) norm_k(
    const float* __restrict__ z1, const float* __restrict__ z2,
    unsigned short* __restrict__ zn, float* __restrict__ S, float* __restrict__ out)
{ phase1(z1, z2, zn, S, out); }

__global__ void __launch_bounds__(256, 2) simexp_k(
    const unsigned short* __restrict__ zn, float* __restrict__ S)
{
    __shared__ __align__(16) unsigned short Bs[2][8192];
    phase2(zn, S, &Bs[0][0]);
}

__global__ void __launch_bounds__(256, 2) finish_k(
    const unsigned short* __restrict__ zn, const float* __restrict__ S,
    float* __restrict__ out)
{
    __shared__ float vals[16];
    phase3(zn, S, out, vals);
}

extern "C" void kernel_launch(void* const* d_in, const int* in_sizes, int n_in,
                              void* d_out, int out_size, void* d_ws, size_t ws_size,
                              hipStream_t stream)
{
    const float* z1 = (const float*)d_in[0];
    const float* z2 = (const float*)d_in[1];
    unsigned short* zn = (unsigned short*)d_ws;                              // 4 MB
    float* S = (float*)((char*)d_ws + 8192 * 256 * sizeof(unsigned short));  // 32 KB
    float* out = (float*)d_out;

    // Host-only queries (graph-capture safe): pick cooperative grid size or fall back.
    int dev = 0;
    hipGetDevice(&dev);
    int coopOK = 0;
    hipDeviceGetAttribute(&coopOK, hipDeviceAttributeCooperativeLaunch, dev);
    int cus = 0;
    hipDeviceGetAttribute(&cus, hipDeviceAttributeMultiprocessorCount, dev);
    int maxB = 0;
    hipOccupancyMaxActiveBlocksPerMultiprocessor(&maxB, ntxent_fused, 256, 0);

    long long cap = (long long)maxB * (long long)cus;
    int G = (cap >= 512) ? 512 : (int)cap;

    if (coopOK && G >= 128) {
        void* args[] = {(void*)&z1, (void*)&z2, (void*)&zn, (void*)&S, (void*)&out};
        hipError_t err = hipLaunchCooperativeKernel(ntxent_fused, dim3(G), dim3(256),
                                                    args, 0, stream);
        if (err == hipSuccess) return;
    }
    // Fallback: same phases as separate (non-cooperative) kernels.
    norm_k<<<512, 256, 0, stream>>>(z1, z2, zn, S, out);
    simexp_k<<<512, 256, 0, stream>>>(zn, S);
    finish_k<<<512, 256, 0, stream>>>(zn, S, out);
}

// Round 10
// 107.109 us; speedup vs baseline: 1.7074x; 1.7074x over previous
//
#include <hip/hip_runtime.h>

typedef __bf16 bf16x8 __attribute__((ext_vector_type(8)));
typedef float f32x4 __attribute__((ext_vector_type(4)));

#define TWO_LOG2E 2.88539008177792681f   // 2*log2(e): exp(2x) = exp2(x*TWO_LOG2E)

#define GLOADLDS16(g, l) __builtin_amdgcn_global_load_lds(                     \
    (const __attribute__((address_space(1))) void*)(g),                        \
    (__attribute__((address_space(3))) void*)(l), 16, 0, 0)

__device__ __forceinline__ unsigned f2bf(float f) {
    unsigned u = __float_as_uint(f);
    return (u + 0x7FFFu + ((u >> 16) & 1u)) >> 16;   // RNE
}

// ---------------- kernel 1: row-normalize z=[z1;z2] -> bf16 zn[8192][256] ---------------
// Blocks 0..31 also zero S[8192]; block 32 zeroes out[0]. No memset dispatches.
__global__ void __launch_bounds__(256) normalize_kernel(
    const float* __restrict__ z1, const float* __restrict__ z2,
    unsigned short* __restrict__ zn, float* __restrict__ S, float* __restrict__ out)
{
    if (blockIdx.x < 32) S[(blockIdx.x << 8) + threadIdx.x] = 0.f;
    if (blockIdx.x == 32 && threadIdx.x == 0) out[0] = 0.f;

    const int wave = threadIdx.x >> 6, lane = threadIdx.x & 63;
    const int row = (blockIdx.x << 2) + wave;               // 2048 blocks * 4 rows
    const float* src = (row < 4096) ? (z1 + row * 256) : (z2 + (row - 4096) * 256);
    float4 v = ((const float4*)src)[lane];                  // 64 lanes * 4 = 256
    float ss = v.x * v.x + v.y * v.y + v.z * v.z + v.w * v.w;
#pragma unroll
    for (int m = 32; m > 0; m >>= 1) ss += __shfl_xor(ss, m, 64);
    float sc = 1.0f / fmaxf(sqrtf(ss), 1e-8f);
    uint2 w;
    w.x = f2bf(v.x * sc) | (f2bf(v.y * sc) << 16);
    w.y = f2bf(v.z * sc) | (f2bf(v.w * sc) << 16);
    *(uint2*)(zn + row * 256 + (lane << 2)) = w;
}

// ---------------- kernel 2: BARRIER-FREE wave-autonomous sim-exp ------------------------
// Block = ONE wave. 2048 jobs = 128 row-strips(64) x 16 col-runs(512) -> 8 blocks/CU
// (8 x 8KB LDS, 2 waves/SIMD). A = wave's 64 rows x K=256 in registers (128 VGPRs).
// B streams through a wave-PRIVATE 2x4KB LDS double buffer via global_load_lds.
// NO __syncthreads anywhere. ORDERING (the R9 NaN bug): the compiler does NOT model
// global_load_lds's LDS-write -> ds_read dependency, so after issuing the prefetch for
// chunk m+1 we explicitly `s_waitcnt vmcnt(4)` — waits until only the 4 newest loads
// (the prefetch) are in flight => chunk m's staging landed; prefetch never drained
// (AITER-style fine-grained pipeline). Reverse hazard (DMA overwriting LDS still being
// read) is ordered by the compiler's lgkmcnt waits: MFMAs consume ds_read data before
// the next stage into that buffer issues in program order.
__global__ void __launch_bounds__(64, 2) simexp_kernel(
    const unsigned short* __restrict__ zn, float* __restrict__ S)
{
    __shared__ __align__(16) unsigned short Bs[2][2048];    // 2 x 4 KB, wave-private

    const int lane = threadIdx.x;
    const int q = lane >> 4, n16 = lane & 15;
    const int job = blockIdx.x;                 // 0..2047
    const int rowBase = (job >> 4) << 6;        // strip * 64
    const int colRun  = (job & 15) << 9;        // run * 512

    // A: 64 rows x K=256 in registers (frag: row=n16, k=q*8.. within 32-elem step)
    bf16x8 a[4][8];
#pragma unroll
    for (int rt = 0; rt < 4; ++rt)
#pragma unroll
        for (int ks = 0; ks < 8; ++ks)
            a[rt][ks] = *(const bf16x8*)(zn + ((rowBase + (rt << 4) + n16) << 8)
                                            + (ks << 5) + (q << 3));

    // stage chunk m (cc=m>>2, kc=m&3): slot s -> col c=s>>3, dest chunk d=s&7,
    // source k8 = d ^ (c&7)  (XOR swizzle => conflict-free b128 reads)
    auto stage = [&](int m, int buf) {
        const int cc = m >> 2, kc = m & 3;
        const int colBase = colRun + (cc << 5);
        unsigned short* base = &Bs[buf][0];
#pragma unroll
        for (int p = 0; p < 4; ++p) {
            int s = (p << 6) + lane;            // 16B slot 0..255
            int c = s >> 3, d = s & 7;
            int k8 = d ^ (c & 7);
            GLOADLDS16(zn + ((colBase + c) << 8) + (kc << 6) + (k8 << 3),
                       base + (s << 3));
        }
    };

    float rs[4][4];
#pragma unroll
    for (int i = 0; i < 4; ++i)
#pragma unroll
        for (int j = 0; j < 4; ++j) rs[i][j] = 0.f;

    stage(0, 0);
    int buf = 0;

    for (int cc = 0; cc < 16; ++cc) {           // 16 col-chunks of 32
        f32x4 acc[4][2];
#pragma unroll
        for (int rt = 0; rt < 4; ++rt)
#pragma unroll
            for (int ct = 0; ct < 2; ++ct) acc[rt][ct] = (f32x4){0.f, 0.f, 0.f, 0.f};

#pragma unroll
        for (int kc = 0; kc < 4; ++kc) {        // 4 k-chunks of 64
            int m = (cc << 2) + kc + 1;
            if (m < 64) {
                stage(m, buf ^ 1);              // prefetch next chunk, other buffer
                // wait: all but the 4 prefetch loads done => current buf staged
                asm volatile("s_waitcnt vmcnt(4)" ::: "memory");
            } else {
                asm volatile("s_waitcnt vmcnt(0)" ::: "memory");
            }

            const unsigned short* bb = &Bs[buf][0];
#pragma unroll
            for (int ks = 0; ks < 2; ++ks) {    // 2 k-steps of 32
                bf16x8 bf[2];
#pragma unroll
                for (int ct = 0; ct < 2; ++ct) {
                    int c  = (ct << 4) + n16;               // col 0..31
                    int k8 = ((ks << 2) + q) ^ (c & 7);     // swizzled chunk
                    bf[ct] = *(const bf16x8*)(bb + (((c << 3) + k8) << 3));
                }
#pragma unroll
                for (int rt = 0; rt < 4; ++rt)
#pragma unroll
                    for (int ct = 0; ct < 2; ++ct)
                        acc[rt][ct] = __builtin_amdgcn_mfma_f32_16x16x32_bf16(
                            a[rt][(kc << 1) + ks], bf[ct], acc[rt][ct], 0, 0, 0);
            }
            buf ^= 1;
        }

        // epilogue: rowsum += exp(2*dot) — registers only
#pragma unroll
        for (int rt = 0; rt < 4; ++rt)
#pragma unroll
            for (int ct = 0; ct < 2; ++ct)
#pragma unroll
                for (int r = 0; r < 4; ++r)
                    rs[rt][r] += __builtin_amdgcn_exp2f(acc[rt][ct][r] * TWO_LOG2E);
    }

    // flush once per job (C/D layout: col=n16, row=q*4+r)
#pragma unroll
    for (int rt = 0; rt < 4; ++rt)
#pragma unroll
        for (int r = 0; r < 4; ++r) {
            float s = rs[rt][r];
            s += __shfl_xor(s, 1, 64);
            s += __shfl_xor(s, 2, 64);
            s += __shfl_xor(s, 4, 64);
            s += __shfl_xor(s, 8, 64);
            if (n16 == 0) atomicAdd(&S[rowBase + (rt << 4) + (q << 2) + r], s);
        }
}

// ---------------- kernel 3: loss = mean( log(S_i - e^{sim_ii}) - sim_{i,target} ) -------
__global__ void __launch_bounds__(256) finish_kernel(
    const unsigned short* __restrict__ zn, const float* __restrict__ S,
    float* __restrict__ out)
{
    __shared__ float vals[16];
    const int tid = threadIdx.x, lane = tid & 63, wave = tid >> 6;
    const int q = lane >> 4, n16 = lane & 15;
    const int rib = (wave << 2) + q;                // 0..15 rows per block
    const int row = (blockIdx.x << 4) + rib;        // 512 blocks * 16 rows
    const int tar = (row + 4096) & 8191;

    float drr = 0.f, drt = 0.f;
#pragma unroll
    for (int i = 0; i < 4; ++i) {
        int k = (i << 6) + (n16 << 2);
        uint2 ur = *(const uint2*)(zn + (row << 8) + k);
        uint2 ut = *(const uint2*)(zn + (tar << 8) + k);
        float a0 = __uint_as_float(ur.x << 16),  a1 = __uint_as_float(ur.x & 0xFFFF0000u);
        float a2 = __uint_as_float(ur.y << 16),  a3 = __uint_as_float(ur.y & 0xFFFF0000u);
        float b0 = __uint_as_float(ut.x << 16),  b1 = __uint_as_float(ut.x & 0xFFFF0000u);
        float b2 = __uint_as_float(ut.y << 16),  b3 = __uint_as_float(ut.y & 0xFFFF0000u);
        drr += a0 * a0 + a1 * a1 + a2 * a2 + a3 * a3;
        drt += a0 * b0 + a1 * b1 + a2 * b2 + a3 * b3;
    }
#pragma unroll
    for (int m = 1; m <= 8; m <<= 1) {
        drr += __shfl_xor(drr, m, 64);
        drt += __shfl_xor(drt, m, 64);
    }
    if (n16 == 0) {
        float Sv = S[row] - __builtin_amdgcn_exp2f(drr * TWO_LOG2E);  // remove diagonal
        vals[rib] = 0.693147180559945f * __builtin_amdgcn_logf(Sv) - 2.0f * drt;
    }
    __syncthreads();
    if (tid == 0) {
        float s = 0.f;
#pragma unroll
        for (int i = 0; i < 16; ++i) s += vals[i];
        atomicAdd(out, s * (1.0f / 8192.0f));
    }
}

extern "C" void kernel_launch(void* const* d_in, const int* in_sizes, int n_in,
                              void* d_out, int out_size, void* d_ws, size_t ws_size,
                              hipStream_t stream)
{
    const float* z1 = (const float*)d_in[0];
    const float* z2 = (const float*)d_in[1];
    unsigned short* zn = (unsigned short*)d_ws;                              // 4 MB
    float* S = (float*)((char*)d_ws + 8192 * 256 * sizeof(unsigned short));  // 32 KB
    float* out = (float*)d_out;

    normalize_kernel<<<2048, 256, 0, stream>>>(z1, z2, zn, S, out);
    simexp_kernel<<<2048, 64, 0, stream>>>(zn, S);
    finish_kernel<<<512, 256, 0, stream>>>(zn, S, out);
}